// Round 2
// baseline (1130.253 us; speedup 1.0000x reference)
//
#include <hip/hip_runtime.h>
#include <hip/hip_bf16.h>

// EdgeGCNV2: h = x@Wg; GAT edge softmax + scatter; C1 = H@gat_out (bf16 MFMA);
// out = leaky(C1@We + be)@Wl.
// Sizes fixed: N_items=16384, F_in=Hd=128, Do=64, N_nodes=8192, E=524288.
// R1 fix: edge_index is int32 in the harness (integer inputs -> const int*),
// NOT int64 as in the reference. R0 read it as long long -> OOB fault.
// Also: ws footprint cut 25.4 MB -> 16.3 MB by aliasing Gt/C1 onto dead h/gacc.

#define NEG 0.2f
#define N_ITEMS 16384
#define N_NODES 8192
#define E_EDGES 524288
#define HD 128

typedef float f32x4 __attribute__((ext_vector_type(4)));
typedef short bf16x8 __attribute__((ext_vector_type(8)));

__device__ __forceinline__ float leaky(float v) { return v >= 0.0f ? v : NEG * v; }

__device__ __forceinline__ unsigned short f2bf(float f) {  // RNE fp32->bf16
  unsigned int u = __float_as_uint(f);
  u += 0x7FFFu + ((u >> 16) & 1u);
  return (unsigned short)(u >> 16);
}

// order-preserving float->uint key for atomicMax (init key 0 is below all finite keys)
__device__ __forceinline__ unsigned int fkey(float f) {
  unsigned int b = __float_as_uint(f);
  return b ^ (unsigned int)(((int)b >> 31) | 0x80000000);
}
__device__ __forceinline__ float funkey(unsigned int k) {
  unsigned int b = (k & 0x80000000u) ? (k ^ 0x80000000u) : ~k;
  return __uint_as_float(b);
}

// ---------------- zero a range of float4s ----------------
__global__ __launch_bounds__(256) void k_zero(f32x4* p, int n4) {
  int i = blockIdx.x * 256 + threadIdx.x;
  int stride = gridDim.x * 256;
  f32x4 z = {0.0f, 0.0f, 0.0f, 0.0f};
  for (; i < n4; i += stride) p[i] = z;
}

// ---------------- h = x @ W_gat  (thread = 1 row x 4 cols) ----------------
__global__ __launch_bounds__(256) void k_h(const float* __restrict__ x,
                                           const float* __restrict__ Wg,
                                           float* __restrict__ h) {
  int gid = blockIdx.x * 256 + threadIdx.x;      // 16384*32 threads
  int row = gid >> 5;
  int c4 = (gid & 31) * 4;
  const float* xr = x + (size_t)row * 128;
  f32x4 acc = {0.0f, 0.0f, 0.0f, 0.0f};
  for (int k = 0; k < 128; k++) {
    float xv = xr[k];
    f32x4 w = *(const f32x4*)&Wg[k * 128 + c4];
    acc += xv * w;
  }
  *(f32x4*)&h[(size_t)row * 128 + c4] = acc;
}

// ---------------- hs = h@a_src, hd = h@a_dst  (wave per row) ----------------
__global__ __launch_bounds__(256) void k_hsd(const float* __restrict__ h,
                                             const float* __restrict__ a_src,
                                             const float* __restrict__ a_dst,
                                             float* __restrict__ hs, float* __restrict__ hd) {
  int r = blockIdx.x * 4 + (threadIdx.x >> 6);
  int lane = threadIdx.x & 63;
  float v0 = h[(size_t)r * 128 + lane];
  float v1 = h[(size_t)r * 128 + 64 + lane];
  float s = v0 * a_src[lane] + v1 * a_src[64 + lane];
  float d = v0 * a_dst[lane] + v1 * a_dst[64 + lane];
  for (int off = 32; off; off >>= 1) { s += __shfl_down(s, off); d += __shfl_down(d, off); }
  if (lane == 0) { hs[r] = s; hd[r] = d; }
}

// ---------------- edge pass 1: segment max of alpha ----------------
__global__ __launch_bounds__(256) void k_amax(const int* __restrict__ ei,
                                              const float* __restrict__ hs,
                                              const float* __restrict__ hd,
                                              unsigned int* __restrict__ mkey) {
  int e = blockIdx.x * 256 + threadIdx.x;
  if (e >= E_EDGES + N_ITEMS) return;
  int s, d;
  if (e < E_EDGES) { s = ei[e]; d = ei[E_EDGES + e]; } else { s = d = e - E_EDGES; }
  float a = leaky(hs[s] + hd[d]);
  atomicMax(&mkey[d], fkey(a));
}

// ---------------- edge pass 2: denom = segment sum of exp(alpha - m) ----------------
__global__ __launch_bounds__(256) void k_denom(const int* __restrict__ ei,
                                               const float* __restrict__ hs,
                                               const float* __restrict__ hd,
                                               const unsigned int* __restrict__ mkey,
                                               float* __restrict__ denom) {
  int e = blockIdx.x * 256 + threadIdx.x;
  if (e >= E_EDGES + N_ITEMS) return;
  int s, d;
  if (e < E_EDGES) { s = ei[e]; d = ei[E_EDGES + e]; } else { s = d = e - E_EDGES; }
  float a = leaky(hs[s] + hd[d]);
  float m = funkey(mkey[d]);
  atomicAdd(&denom[d], __expf(a - m));
}

// ---------------- edge pass 3: gacc[dst] += w * h[src]  (wave per edge) ----------------
__global__ __launch_bounds__(256) void k_scatter(const int* __restrict__ ei,
                                                 const float* __restrict__ hs,
                                                 const float* __restrict__ hd,
                                                 const unsigned int* __restrict__ mkey,
                                                 const float* __restrict__ denom,
                                                 const float* __restrict__ h,
                                                 float* __restrict__ gacc) {
  int wid = blockIdx.x * 4 + (threadIdx.x >> 6);
  int lane = threadIdx.x & 63;
  if (wid >= E_EDGES + N_ITEMS) return;
  int s, d;
  if (wid < E_EDGES) { s = ei[wid]; d = ei[E_EDGES + wid]; } else { s = d = wid - E_EDGES; }
  float a = leaky(hs[s] + hd[d]);
  float w = __expf(a - funkey(mkey[d])) / denom[d];
  float v0 = h[(size_t)s * 128 + lane];
  float v1 = h[(size_t)s * 128 + 64 + lane];
  atomicAdd(&gacc[(size_t)d * 128 + lane], w * v0);
  atomicAdd(&gacc[(size_t)d * 128 + 64 + lane], w * v1);
}

// ---------------- gat_out + b_gat -> bf16, transposed Gt[128][16384] ----------------
__global__ __launch_bounds__(256) void k_cvt(const float* __restrict__ gacc,
                                             const float* __restrict__ b_gat,
                                             unsigned short* __restrict__ Gt) {
  __shared__ unsigned short T[128][65];
  int r0 = blockIdx.x * 64;
  int t = threadIdx.x;
#pragma unroll
  for (int i = 0; i < 32; i++) {
    int flat = i * 256 + t;
    int r = flat >> 7, c = flat & 127;
    float v = gacc[(size_t)(r0 + r) * 128 + c] + b_gat[c];
    T[c][r] = f2bf(v);
  }
  __syncthreads();
#pragma unroll
  for (int i = 0; i < 32; i++) {
    int flat = i * 256 + t;
    int c = flat >> 6, r = flat & 63;
    Gt[(size_t)c * 16384 + r0 + r] = T[c][r];
  }
}

// ---------------- C1 = H @ gat_out  (bf16 MFMA, BM=32, BK=64, splitK=4) ----------------
#define GB_LDA 72
#define GB_LDB 72

__device__ __forceinline__ f32x4 mfma16(bf16x8 a, bf16x8 b, f32x4 c) {
  return __builtin_amdgcn_mfma_f32_16x16x32_bf16(a, b, c, 0, 0, 0);
}

__global__ __launch_bounds__(256, 4) void k_gemm_big(const float* __restrict__ Hm,
                                                     const unsigned short* __restrict__ Gt,
                                                     float* __restrict__ C1) {
  __shared__ __align__(16) unsigned short As[32 * GB_LDA];
  __shared__ __align__(16) unsigned short Bs[128 * GB_LDB];

  // XCD swizzle: ksplit constant per XCD (bid%8 & 3), so each XCD's L2 keeps one 1MB B-slice
  const int g = blockIdx.x & 7;
  const int ksplit = g & 3;
  const int mt = ((blockIdx.x >> 3) << 1) | (g >> 2);   // 0..255
  const int m0 = mt * 32;
  const int kbeg = ksplit * 4096;

  const int t = threadIdx.x;
  const int lane = t & 63;
  const int wave = t >> 6;
  const int wm = wave & 1;   // M slice (16 rows)
  const int wn = wave >> 1;  // N half (64 cols)

  f32x4 acc0 = {0,0,0,0}, acc1 = {0,0,0,0}, acc2 = {0,0,0,0}, acc3 = {0,0,0,0};

  // A staging: thread -> row (t>>3), 8 floats at k-offset (t&7)*8
  const int ar = t >> 3;
  const int ac = (t & 7) * 8;
  const float* Ap = Hm + (size_t)(m0 + ar) * 16384 + ac + kbeg;
  unsigned short* AsW = &As[ar * GB_LDA + ac];

  // B staging: thread -> col (t>>1), 32 bf16 at k-offset (t&1)*32
  const int bc = t >> 1;
  const int bsg = (t & 1) * 32;
  const unsigned short* Bp = Gt + (size_t)bc * 16384 + bsg + kbeg;
  unsigned short* BsW = &Bs[bc * GB_LDB + bsg];

  // fragment read bases
  const unsigned short* AsR = &As[(wm * 16 + (lane & 15)) * GB_LDA + (lane >> 4) * 8];
  const unsigned short* BsR = &Bs[(wn * 64 + (lane & 15)) * GB_LDB + (lane >> 4) * 8];

  for (int k0 = 0; k0 < 4096; k0 += 64) {
    f32x4 a0 = *(const f32x4*)(Ap + k0);
    f32x4 a1 = *(const f32x4*)(Ap + k0 + 4);
    bf16x8 b0 = *(const bf16x8*)(Bp + k0);
    bf16x8 b1 = *(const bf16x8*)(Bp + k0 + 8);
    bf16x8 b2 = *(const bf16x8*)(Bp + k0 + 16);
    bf16x8 b3 = *(const bf16x8*)(Bp + k0 + 24);
    bf16x8 av;
    av[0] = (short)f2bf(a0[0]); av[1] = (short)f2bf(a0[1]);
    av[2] = (short)f2bf(a0[2]); av[3] = (short)f2bf(a0[3]);
    av[4] = (short)f2bf(a1[0]); av[5] = (short)f2bf(a1[1]);
    av[6] = (short)f2bf(a1[2]); av[7] = (short)f2bf(a1[3]);

    __syncthreads();
    *(bf16x8*)AsW = av;
    *(bf16x8*)(BsW)      = b0;
    *(bf16x8*)(BsW + 8)  = b1;
    *(bf16x8*)(BsW + 16) = b2;
    *(bf16x8*)(BsW + 24) = b3;
    __syncthreads();

#pragma unroll
    for (int kk = 0; kk < 2; kk++) {
      bf16x8 af = *(const bf16x8*)(AsR + kk * 32);
      acc0 = mfma16(af, *(const bf16x8*)(BsR + kk * 32), acc0);
      acc1 = mfma16(af, *(const bf16x8*)(BsR + 16 * GB_LDB + kk * 32), acc1);
      acc2 = mfma16(af, *(const bf16x8*)(BsR + 32 * GB_LDB + kk * 32), acc2);
      acc3 = mfma16(af, *(const bf16x8*)(BsR + 48 * GB_LDB + kk * 32), acc3);
    }
  }

  // epilogue: C/D layout col=lane&15, row=(lane>>4)*4+reg  -> atomicAdd (split-K)
  const int erow = m0 + wm * 16 + ((lane >> 4) << 2);
  const int ecol = wn * 64 + (lane & 15);
  f32x4 accs[4] = {acc0, acc1, acc2, acc3};
#pragma unroll
  for (int nt = 0; nt < 4; nt++)
#pragma unroll
    for (int r = 0; r < 4; r++)
      atomicAdd(&C1[(size_t)(erow + r) * 128 + ecol + nt * 16], accs[nt][r]);
}

// ---------------- out = leaky(C1@We + be) @ Wl ----------------
__global__ __launch_bounds__(256) void k_final(const float* __restrict__ C1,
                                               const float* __restrict__ We,
                                               const float* __restrict__ be,
                                               const float* __restrict__ Wl,
                                               float* __restrict__ out) {
  __shared__ float t1[32][132];
  const int t = threadIdx.x;
  const int r0 = blockIdx.x * 32;
  const int r = t >> 3;
  const int cg = (t & 7) * 16;
  const float* cr = C1 + (size_t)(r0 + r) * 128;
  f32x4 acc[4] = {{0,0,0,0},{0,0,0,0},{0,0,0,0},{0,0,0,0}};
  for (int k = 0; k < 128; k++) {
    float cv = cr[k];
    const f32x4* wrow = (const f32x4*)&We[k * 128 + cg];
    acc[0] += cv * wrow[0];
    acc[1] += cv * wrow[1];
    acc[2] += cv * wrow[2];
    acc[3] += cv * wrow[3];
  }
#pragma unroll
  for (int j = 0; j < 16; j++) {
    float v = acc[j >> 2][j & 3] + be[cg + j];
    t1[r][cg + j] = leaky(v);
  }
  __syncthreads();
  const int c8 = (t & 7) * 8;
  f32x4 acc2[2] = {{0,0,0,0},{0,0,0,0}};
  for (int k = 0; k < 128; k++) {
    float tv = t1[r][k];
    const f32x4* wl = (const f32x4*)&Wl[k * 64 + c8];
    acc2[0] += tv * wl[0];
    acc2[1] += tv * wl[1];
  }
#pragma unroll
  for (int j = 0; j < 8; j++)
    out[(size_t)(r0 + r) * 64 + c8 + j] = acc2[j >> 2][j & 3];
}

// ---------------- launch ----------------
extern "C" void kernel_launch(void* const* d_in, const int* in_sizes, int n_in,
                              void* d_out, int out_size, void* d_ws, size_t ws_size,
                              hipStream_t stream) {
  const float* x      = (const float*)d_in[0];
  const float* Hm     = (const float*)d_in[1];
  const int*   ei     = (const int*)d_in[2];     // int32 in harness (NOT int64)
  const float* Wg     = (const float*)d_in[3];
  const float* a_src  = (const float*)d_in[4];
  const float* a_dst  = (const float*)d_in[5];
  const float* b_gat  = (const float*)d_in[6];
  const float* We     = (const float*)d_in[7];
  const float* be     = (const float*)d_in[8];
  const float* Wl     = (const float*)d_in[9];
  float* out = (float*)d_out;

  // ws layout (16.3 MB total), with aliasing of dead buffers:
  //   [0        , 8 MB )  gacc [16384,128] f32      -> later reused as C1 [8192,128] f32 (4 MB)
  //   [8 MB     , +64K )  denom
  //   [+64K     , +64K )  mkey
  //   [+128K    , +64K )  hs
  //   [+192K    , +64K )  hd
  //   [8 MB+256K, 8 MB )  h [16384,128] f32         -> later reused as Gt bf16 [128,16384] (4 MB)
  char* ws = (char*)d_ws;
  float*          gacc  = (float*)(ws);
  float*          denom = (float*)(ws + 8388608);
  unsigned int*   mkey  = (unsigned int*)(ws + 8454144);
  float*          hs    = (float*)(ws + 8519680);
  float*          hd    = (float*)(ws + 8585216);
  float*          h     = (float*)(ws + 8650752);
  unsigned short* Gt    = (unsigned short*)(ws + 8650752);   // aliases h (h dead after k_scatter)
  float*          C1    = (float*)(ws);                      // aliases gacc (dead after k_cvt)

  // zero gacc+denom+mkey (contiguous 8519680 B = 532480 float4s)
  k_zero<<<2080, 256, 0, stream>>>((f32x4*)ws, 532480);
  k_h<<<2048, 256, 0, stream>>>(x, Wg, h);
  k_hsd<<<4096, 256, 0, stream>>>(h, a_src, a_dst, hs, hd);
  const int EN = E_EDGES + N_ITEMS;
  k_amax<<<(EN + 255) / 256, 256, 0, stream>>>(ei, hs, hd, mkey);
  k_denom<<<(EN + 255) / 256, 256, 0, stream>>>(ei, hs, hd, mkey, denom);
  k_scatter<<<EN / 4, 256, 0, stream>>>(ei, hs, hd, mkey, denom, h, gacc);
  k_cvt<<<256, 256, 0, stream>>>(gacc, b_gat, Gt);
  // zero C1 (4 MB = 262144 float4s) — gacc is dead now, C1 aliases it
  k_zero<<<1024, 256, 0, stream>>>((f32x4*)C1, 262144);
  k_gemm_big<<<1024, 256, 0, stream>>>(Hm, Gt, C1);
  k_final<<<256, 256, 0, stream>>>(C1, We, be, Wl, out);
}

// Round 3
// 957.541 us; speedup vs baseline: 1.1804x; 1.1804x over previous
//
#include <hip/hip_runtime.h>
#include <hip/hip_bf16.h>

// EdgeGCNV2: h = x@Wg; GAT edge softmax + scatter; C1 = H@gat_out (bf16 MFMA);
// out = leaky(C1@We + be)@Wl.
// Sizes fixed: N_items=16384, F_in=Hd=128, Do=64, N_nodes=8192, E=524288.
// R2: counting-sort edges by dst + fused online-softmax aggregation (one wave
// per dst, no value atomics) replaces the 3-pass atomic edge pipeline.

#define NEG 0.2f
#define N_ITEMS 16384
#define N_NODES 8192
#define E_EDGES 524288
#define HD 128

typedef float f32x4 __attribute__((ext_vector_type(4)));
typedef short bf16x8 __attribute__((ext_vector_type(8)));

__device__ __forceinline__ float leaky(float v) { return v >= 0.0f ? v : NEG * v; }

__device__ __forceinline__ unsigned short f2bf(float f) {  // RNE fp32->bf16
  unsigned int u = __float_as_uint(f);
  u += 0x7FFFu + ((u >> 16) & 1u);
  return (unsigned short)(u >> 16);
}

// ---------------- zero a range of float4s ----------------
__global__ __launch_bounds__(256) void k_zero(f32x4* p, int n4) {
  int i = blockIdx.x * 256 + threadIdx.x;
  int stride = gridDim.x * 256;
  f32x4 z = {0.0f, 0.0f, 0.0f, 0.0f};
  for (; i < n4; i += stride) p[i] = z;
}

// ---------------- h = x @ W_gat  (thread = 1 row x 4 cols) ----------------
__global__ __launch_bounds__(256) void k_h(const float* __restrict__ x,
                                           const float* __restrict__ Wg,
                                           float* __restrict__ h) {
  int gid = blockIdx.x * 256 + threadIdx.x;      // 16384*32 threads
  int row = gid >> 5;
  int c4 = (gid & 31) * 4;
  const float* xr = x + (size_t)row * 128;
  f32x4 acc = {0.0f, 0.0f, 0.0f, 0.0f};
  for (int k = 0; k < 128; k++) {
    float xv = xr[k];
    f32x4 w = *(const f32x4*)&Wg[k * 128 + c4];
    acc += xv * w;
  }
  *(f32x4*)&h[(size_t)row * 128 + c4] = acc;
}

// ---------------- hs = h@a_src, hd = h@a_dst  (wave per row) ----------------
__global__ __launch_bounds__(256) void k_hsd(const float* __restrict__ h,
                                             const float* __restrict__ a_src,
                                             const float* __restrict__ a_dst,
                                             float* __restrict__ hs, float* __restrict__ hd) {
  int r = blockIdx.x * 4 + (threadIdx.x >> 6);
  int lane = threadIdx.x & 63;
  float v0 = h[(size_t)r * 128 + lane];
  float v1 = h[(size_t)r * 128 + 64 + lane];
  float s = v0 * a_src[lane] + v1 * a_src[64 + lane];
  float d = v0 * a_dst[lane] + v1 * a_dst[64 + lane];
  for (int off = 32; off; off >>= 1) { s += __shfl_down(s, off); d += __shfl_down(d, off); }
  if (lane == 0) { hs[r] = s; hd[r] = d; }
}

// ---------------- histogram of dst ----------------
__global__ __launch_bounds__(256) void k_hist(const int* __restrict__ ei,
                                              int* __restrict__ cnt) {
  int e = blockIdx.x * 256 + threadIdx.x;
  if (e < E_EDGES) atomicAdd(&cnt[ei[E_EDGES + e]], 1);
}

// ---------------- exclusive scan of cnt[16384] -> off[16385], cur=off ------
__global__ __launch_bounds__(256) void k_scan(const int* __restrict__ cnt,
                                              int* __restrict__ off,
                                              int* __restrict__ cur) {
  __shared__ int part[256];
  int t = threadIdx.x;
  int base = t * 64;
  int sum = 0;
  for (int i = 0; i < 64; i++) sum += cnt[base + i];
  part[t] = sum;
  __syncthreads();
  for (int o = 1; o < 256; o <<= 1) {
    int v = (t >= o) ? part[t - o] : 0;
    __syncthreads();
    part[t] += v;
    __syncthreads();
  }
  int run = (t > 0) ? part[t - 1] : 0;
  for (int i = 0; i < 64; i++) {
    off[base + i] = run;
    cur[base + i] = run;
    run += cnt[base + i];
  }
  if (t == 255) off[16384] = run;
}

// ---------------- scatter srcs into dst-sorted order ----------------
__global__ __launch_bounds__(256) void k_reorder(const int* __restrict__ ei,
                                                 int* __restrict__ cur,
                                                 int* __restrict__ es) {
  int e = blockIdx.x * 256 + threadIdx.x;
  if (e >= E_EDGES) return;
  int d = ei[E_EDGES + e];
  int pos = atomicAdd(&cur[d], 1);
  es[pos] = ei[e];
}

// ---------------- fused online-softmax aggregation: wave per dst ----------
// gat[d] = (sum_e w_e * h[src_e] + w_self * h[d]) / l  + b_gat,  softmax over
// incoming edges + self-loop with running-max rescaling.
__global__ __launch_bounds__(256) void k_agg(const int* __restrict__ es,
                                             const int* __restrict__ off,
                                             const float* __restrict__ hs,
                                             const float* __restrict__ hd,
                                             const float* __restrict__ h,
                                             const float* __restrict__ b_gat,
                                             float* __restrict__ gat) {
  int d = blockIdx.x * 4 + (threadIdx.x >> 6);   // 4096 blocks
  int lane = threadIdx.x & 63;
  int beg = off[d], end = off[d + 1];
  float hdd = hd[d];
  // self-loop init
  float m = leaky(hs[d] + hdd);
  float l = 1.0f;
  float acc0 = h[(size_t)d * 128 + lane];
  float acc1 = h[(size_t)d * 128 + 64 + lane];

  for (int j0 = beg; j0 < end; j0 += 64) {
    int n = end - j0; if (n > 64) n = 64;
    int s = (lane < n) ? es[j0 + lane] : 0;
    float a = (lane < n) ? leaky(hs[s] + hdd) : -3.0e38f;
    // chunk max
    float cm = a;
    for (int o = 32; o; o >>= 1) cm = fmaxf(cm, __shfl_down(cm, o));
    cm = __shfl(cm, 0);
    float nm = fmaxf(m, cm);
    float scale = __expf(m - nm);
    acc0 *= scale; acc1 *= scale; l *= scale;
    m = nm;
    float w = (lane < n) ? __expf(a - nm) : 0.0f;
    float wsum = w;
    for (int o = 32; o; o >>= 1) wsum += __shfl_down(wsum, o);
    l += __shfl(wsum, 0);
    for (int j = 0; j < n; j++) {
      float wj = __shfl(w, j);
      int sj = __shfl(s, j);
      const float* hr = h + (size_t)sj * 128;
      acc0 = fmaf(wj, hr[lane], acc0);
      acc1 = fmaf(wj, hr[64 + lane], acc1);
    }
  }
  float inv = 1.0f / l;
  gat[(size_t)d * 128 + lane]      = acc0 * inv + b_gat[lane];
  gat[(size_t)d * 128 + 64 + lane] = acc1 * inv + b_gat[64 + lane];
}

// ---------------- gat (fp32, bias included) -> bf16 transposed Gt[128][16384] ----
__global__ __launch_bounds__(256) void k_cvt(const float* __restrict__ gat,
                                             unsigned short* __restrict__ Gt) {
  __shared__ unsigned short T[128][65];
  int r0 = blockIdx.x * 64;
  int t = threadIdx.x;
#pragma unroll
  for (int i = 0; i < 32; i++) {
    int flat = i * 256 + t;
    int r = flat >> 7, c = flat & 127;
    T[c][r] = f2bf(gat[(size_t)(r0 + r) * 128 + c]);
  }
  __syncthreads();
#pragma unroll
  for (int i = 0; i < 32; i++) {
    int flat = i * 256 + t;
    int c = flat >> 6, r = flat & 63;
    Gt[(size_t)c * 16384 + r0 + r] = T[c][r];
  }
}

// ---------------- C1 = H @ gat_out  (bf16 MFMA, BM=32, BK=64, splitK=4) ----------------
#define GB_LDA 72
#define GB_LDB 72

__device__ __forceinline__ f32x4 mfma16(bf16x8 a, bf16x8 b, f32x4 c) {
  return __builtin_amdgcn_mfma_f32_16x16x32_bf16(a, b, c, 0, 0, 0);
}

__global__ __launch_bounds__(256, 4) void k_gemm_big(const float* __restrict__ Hm,
                                                     const unsigned short* __restrict__ Gt,
                                                     float* __restrict__ C1) {
  __shared__ __align__(16) unsigned short As[32 * GB_LDA];
  __shared__ __align__(16) unsigned short Bs[128 * GB_LDB];

  // XCD swizzle: ksplit constant per XCD (bid%8 & 3), so each XCD's L2 keeps one 1MB B-slice
  const int g = blockIdx.x & 7;
  const int ksplit = g & 3;
  const int mt = ((blockIdx.x >> 3) << 1) | (g >> 2);   // 0..255
  const int m0 = mt * 32;
  const int kbeg = ksplit * 4096;

  const int t = threadIdx.x;
  const int lane = t & 63;
  const int wave = t >> 6;
  const int wm = wave & 1;   // M slice (16 rows)
  const int wn = wave >> 1;  // N half (64 cols)

  f32x4 acc0 = {0,0,0,0}, acc1 = {0,0,0,0}, acc2 = {0,0,0,0}, acc3 = {0,0,0,0};

  const int ar = t >> 3;
  const int ac = (t & 7) * 8;
  const float* Ap = Hm + (size_t)(m0 + ar) * 16384 + ac + kbeg;
  unsigned short* AsW = &As[ar * GB_LDA + ac];

  const int bc = t >> 1;
  const int bsg = (t & 1) * 32;
  const unsigned short* Bp = Gt + (size_t)bc * 16384 + bsg + kbeg;
  unsigned short* BsW = &Bs[bc * GB_LDB + bsg];

  const unsigned short* AsR = &As[(wm * 16 + (lane & 15)) * GB_LDA + (lane >> 4) * 8];
  const unsigned short* BsR = &Bs[(wn * 64 + (lane & 15)) * GB_LDB + (lane >> 4) * 8];

  for (int k0 = 0; k0 < 4096; k0 += 64) {
    f32x4 a0 = *(const f32x4*)(Ap + k0);
    f32x4 a1 = *(const f32x4*)(Ap + k0 + 4);
    bf16x8 b0 = *(const bf16x8*)(Bp + k0);
    bf16x8 b1 = *(const bf16x8*)(Bp + k0 + 8);
    bf16x8 b2 = *(const bf16x8*)(Bp + k0 + 16);
    bf16x8 b3 = *(const bf16x8*)(Bp + k0 + 24);
    bf16x8 av;
    av[0] = (short)f2bf(a0[0]); av[1] = (short)f2bf(a0[1]);
    av[2] = (short)f2bf(a0[2]); av[3] = (short)f2bf(a0[3]);
    av[4] = (short)f2bf(a1[0]); av[5] = (short)f2bf(a1[1]);
    av[6] = (short)f2bf(a1[2]); av[7] = (short)f2bf(a1[3]);

    __syncthreads();
    *(bf16x8*)AsW = av;
    *(bf16x8*)(BsW)      = b0;
    *(bf16x8*)(BsW + 8)  = b1;
    *(bf16x8*)(BsW + 16) = b2;
    *(bf16x8*)(BsW + 24) = b3;
    __syncthreads();

#pragma unroll
    for (int kk = 0; kk < 2; kk++) {
      bf16x8 af = *(const bf16x8*)(AsR + kk * 32);
      acc0 = mfma16(af, *(const bf16x8*)(BsR + kk * 32), acc0);
      acc1 = mfma16(af, *(const bf16x8*)(BsR + 16 * GB_LDB + kk * 32), acc1);
      acc2 = mfma16(af, *(const bf16x8*)(BsR + 32 * GB_LDB + kk * 32), acc2);
      acc3 = mfma16(af, *(const bf16x8*)(BsR + 48 * GB_LDB + kk * 32), acc3);
    }
  }

  // epilogue: C/D layout col=lane&15, row=(lane>>4)*4+reg  -> atomicAdd (split-K)
  const int erow = m0 + wm * 16 + ((lane >> 4) << 2);
  const int ecol = wn * 64 + (lane & 15);
  f32x4 accs[4] = {acc0, acc1, acc2, acc3};
#pragma unroll
  for (int nt = 0; nt < 4; nt++)
#pragma unroll
    for (int r = 0; r < 4; r++)
      atomicAdd(&C1[(size_t)(erow + r) * 128 + ecol + nt * 16], accs[nt][r]);
}

// ---------------- out = leaky(C1@We + be) @ Wl ----------------
__global__ __launch_bounds__(256) void k_final(const float* __restrict__ C1,
                                               const float* __restrict__ We,
                                               const float* __restrict__ be,
                                               const float* __restrict__ Wl,
                                               float* __restrict__ out) {
  __shared__ float t1[32][132];
  const int t = threadIdx.x;
  const int r0 = blockIdx.x * 32;
  const int r = t >> 3;
  const int cg = (t & 7) * 16;
  const float* cr = C1 + (size_t)(r0 + r) * 128;
  f32x4 acc[4] = {{0,0,0,0},{0,0,0,0},{0,0,0,0},{0,0,0,0}};
  for (int k = 0; k < 128; k++) {
    float cv = cr[k];
    const f32x4* wrow = (const f32x4*)&We[k * 128 + cg];
    acc[0] += cv * wrow[0];
    acc[1] += cv * wrow[1];
    acc[2] += cv * wrow[2];
    acc[3] += cv * wrow[3];
  }
#pragma unroll
  for (int j = 0; j < 16; j++) {
    float v = acc[j >> 2][j & 3] + be[cg + j];
    t1[r][cg + j] = leaky(v);
  }
  __syncthreads();
  const int c8 = (t & 7) * 8;
  f32x4 acc2[2] = {{0,0,0,0},{0,0,0,0}};
  for (int k = 0; k < 128; k++) {
    float tv = t1[r][k];
    const f32x4* wl = (const f32x4*)&Wl[k * 64 + c8];
    acc2[0] += tv * wl[0];
    acc2[1] += tv * wl[1];
  }
#pragma unroll
  for (int j = 0; j < 8; j++)
    out[(size_t)(r0 + r) * 64 + c8 + j] = acc2[j >> 2][j & 3];
}

// ---------------- launch ----------------
extern "C" void kernel_launch(void* const* d_in, const int* in_sizes, int n_in,
                              void* d_out, int out_size, void* d_ws, size_t ws_size,
                              hipStream_t stream) {
  const float* x      = (const float*)d_in[0];
  const float* Hm     = (const float*)d_in[1];
  const int*   ei     = (const int*)d_in[2];     // int32 in harness (NOT int64)
  const float* Wg     = (const float*)d_in[3];
  const float* a_src  = (const float*)d_in[4];
  const float* a_dst  = (const float*)d_in[5];
  const float* b_gat  = (const float*)d_in[6];
  const float* We     = (const float*)d_in[7];
  const float* be     = (const float*)d_in[8];
  const float* Wl     = (const float*)d_in[9];
  float* out = (float*)d_out;

  // ws layout (~19.3 MB):
  //   [0       , 8M )  h [16384,128] f32      -> reused as Gt bf16 [128,16384] (4 MB)
  //   [8M      , 16M)  gat [16384,128] f32    -> reused as C1 [8192,128] f32 (4 MB)
  //   [16M     , +64K) hs
  //   [+64K    , +64K) hd
  //   [+128K   , +64K) cnt
  //   [+192K   ,+128K) off (16385 ints)
  //   [+320K   , +64K) cur
  //   [+384K   , +2M ) es (sorted srcs)
  char* ws = (char*)d_ws;
  float*          h     = (float*)(ws);
  float*          gat   = (float*)(ws + 8388608);
  float*          hs    = (float*)(ws + 16777216);
  float*          hd    = (float*)(ws + 16842752);
  int*            cnt   = (int*)  (ws + 16908288);
  int*            off   = (int*)  (ws + 16973824);
  int*            cur   = (int*)  (ws + 17104896);
  int*            es    = (int*)  (ws + 17170432);
  unsigned short* Gt    = (unsigned short*)ws;        // aliases h (dead after k_agg... used by k_cvt write)
  float*          C1    = (float*)(ws + 8388608);     // aliases gat (dead after k_cvt)

  k_zero<<<64, 256, 0, stream>>>((f32x4*)cnt, 4096);  // zero cnt (64 KB)
  k_h<<<2048, 256, 0, stream>>>(x, Wg, h);
  k_hsd<<<4096, 256, 0, stream>>>(h, a_src, a_dst, hs, hd);
  k_hist<<<E_EDGES / 256, 256, 0, stream>>>(ei, cnt);
  k_scan<<<1, 256, 0, stream>>>(cnt, off, cur);
  k_reorder<<<E_EDGES / 256, 256, 0, stream>>>(ei, cur, es);
  k_agg<<<4096, 256, 0, stream>>>(es, off, hs, hd, h, b_gat, gat);
  k_cvt<<<256, 256, 0, stream>>>(gat, Gt);            // h region overwritten by Gt here
  k_zero<<<1024, 256, 0, stream>>>((f32x4*)C1, 262144);  // zero C1 (4 MB)
  k_gemm_big<<<1024, 256, 0, stream>>>(Hm, Gt, C1);
  k_final<<<256, 256, 0, stream>>>(C1, We, be, Wl, out);
}